// Round 22
// baseline (237.562 us; speedup 1.0000x reference)
//
#include <hip/hip_runtime.h>

#define NNODES 50000
#define NF 256
#define NH 512
#define MPAD 50048   // 391 * 128
#define NRB 391      // MPAD/128 row-blocks
#define BN_EPS 1e-5f
#define CAP 96       // bucket capacity; P(deg>96 | E=800K uniform) < 1e-40, overflow -> err sentinel

typedef unsigned short u16;
typedef __attribute__((ext_vector_type(8))) short bf16x8;
typedef __attribute__((ext_vector_type(4))) float f32x4;

__device__ __forceinline__ float bf2f(u16 u) {
  union { unsigned int i; float f; } v; v.i = ((unsigned int)u) << 16; return v.f;
}
__device__ __forceinline__ u16 f2bf(float f) {
  union { float ff; unsigned int i; } v; v.ff = f;
  unsigned int r = v.i + 0x7FFFu + ((v.i >> 16) & 1u);
  return (u16)(r >> 16);
}

__device__ __forceinline__ void async16(const void* g, void* l) {
  __builtin_amdgcn_global_load_lds(
      (const __attribute__((address_space(1))) unsigned int*)g,
      (__attribute__((address_space(3))) unsigned int*)l, 16, 0, 0);
}

// ---------------- conv_x + transpose_w1: pure streaming ----------------
__global__ __launch_bounds__(256) void conv_tr_kernel(const float* __restrict__ x,
                                                      u16* __restrict__ xbf,
                                                      const float* __restrict__ W1,
                                                      u16* __restrict__ W1t) {
  const int b = blockIdx.x;
  if (b < 2048) {
    const size_t n8 = (size_t)NNODES * NF / 8;
    size_t stride = (size_t)2048 * 256;
    for (size_t i = b * (size_t)256 + threadIdx.x; i < n8; i += stride) {
      float4 a = ((const float4*)x)[2 * i];
      float4 c = ((const float4*)x)[2 * i + 1];
      ushort4 lo, hi;
      lo.x = f2bf(a.x); lo.y = f2bf(a.y); lo.z = f2bf(a.z); lo.w = f2bf(a.w);
      hi.x = f2bf(c.x); hi.y = f2bf(c.y); hi.z = f2bf(c.z); hi.w = f2bf(c.w);
      ((ushort4*)xbf)[2 * i] = lo;
      ((ushort4*)xbf)[2 * i + 1] = hi;
    }
  } else {
    int idx = (b - 2048) * 256 + threadIdx.x;
    int n = idx >> 8;
    int k = idx & 255;
    W1t[(size_t)n * NF + k] = f2bf(W1[(size_t)k * NH + n]);
  }
}

// ---------------- bucket fill: ONE atomic pass replaces hist+scan+fill ----------------
__global__ __launch_bounds__(256) void bucket_fill(const int* __restrict__ ei, int E,
                                                   int* __restrict__ cw,
                                                   int* __restrict__ srcs,
                                                   int* __restrict__ err) {
  __shared__ int sf;
  if (threadIdx.x < 64) {
    unsigned long long bb = __ballot(ei[2 * threadIdx.x + 1] == 0);
    if (threadIdx.x == 0) sf = (bb == ~0ull) ? 1 : 0;
  }
  __syncthreads();
  const int is64 = sf;
  const int gtid = blockIdx.x * 256 + threadIdx.x;
  const int stride = gridDim.x * 256;
  if (is64) {
    const int4* s4 = (const int4*)ei;                 // edges 2p,2p+1 in .x,.z
    const int4* d4 = (const int4*)(ei + 2 * (size_t)E);
    int np = E >> 1;
    for (int p = gtid; p < np; p += stride) {
      int4 sv = s4[p], dv = d4[p];
      if ((unsigned)sv.x < NNODES && (unsigned)dv.x < NNODES) {
        int pos = atomicAdd(&cw[dv.x], 1);
        if (pos < CAP) srcs[(size_t)dv.x * CAP + pos] = sv.x; else err[0] = 4;
      }
      if ((unsigned)sv.z < NNODES && (unsigned)dv.z < NNODES) {
        int pos = atomicAdd(&cw[dv.z], 1);
        if (pos < CAP) srcs[(size_t)dv.z * CAP + pos] = sv.z; else err[0] = 4;
      }
    }
    for (int e = (np << 1) + gtid; e < E; e += stride) {
      int src = ei[2 * e], dst = ei[2 * (size_t)E + 2 * e];
      if ((unsigned)src >= NNODES || (unsigned)dst >= NNODES) continue;
      int pos = atomicAdd(&cw[dst], 1);
      if (pos < CAP) srcs[(size_t)dst * CAP + pos] = src; else err[0] = 4;
    }
  } else {
    const int4* s4 = (const int4*)ei;
    const int4* d4 = (const int4*)(ei + E);
    int np = E >> 2;
    for (int p = gtid; p < np; p += stride) {
      int4 sv = s4[p], dv = d4[p];
      int ss[4] = {sv.x, sv.y, sv.z, sv.w};
      int dd[4] = {dv.x, dv.y, dv.z, dv.w};
#pragma unroll
      for (int j = 0; j < 4; ++j) {
        if ((unsigned)ss[j] < NNODES && (unsigned)dd[j] < NNODES) {
          int pos = atomicAdd(&cw[dd[j]], 1);
          if (pos < CAP) srcs[(size_t)dd[j] * CAP + pos] = ss[j]; else err[0] = 4;
        }
      }
    }
    for (int e = (np << 2) + gtid; e < E; e += stride) {
      int src = ei[e], dst = ei[(size_t)E + e];
      if ((unsigned)src >= NNODES || (unsigned)dst >= NNODES) continue;
      int pos = atomicAdd(&cw[dst], 1);
      if (pos < CAP) srcs[(size_t)dst * CAP + pos] = src; else err[0] = 4;
    }
  }
}

// ---------------- gather-reduce from buckets: 2 nodes/wave, 32 lanes/node ----------------
__global__ __launch_bounds__(256) void gather_kernel(const u16* __restrict__ xbf,
                                                     const int* __restrict__ srcs,
                                                     const int* __restrict__ cw,
                                                     u16* __restrict__ hpad) {
  const int hl = threadIdx.x & 31;
  const int node = blockIdx.x * 8 + (threadIdx.x >> 5);
  if (node >= MPAD) return;
  bf16x8* outp = (bf16x8*)(hpad + (size_t)node * NF + hl * 8);
  if (node >= NNODES) {
    bf16x8 z = {0, 0, 0, 0, 0, 0, 0, 0};
    *outp = z;
    return;
  }
  bf16x8 sv = *(const bf16x8*)(xbf + (size_t)node * NF + hl * 8);
  float acc[8];
#pragma unroll
  for (int j = 0; j < 8; ++j) acc[j] = bf2f((u16)sv[j]);
  int cnt = cw[node];
  if (cnt > CAP) cnt = CAP;
  const int* lst = srcs + (size_t)node * CAP;
  int e = 0;
  for (; e + 3 < cnt; e += 4) {
    bf16x8 v[4];
#pragma unroll
    for (int u = 0; u < 4; ++u)
      v[u] = *(const bf16x8*)(xbf + (size_t)lst[e + u] * NF + hl * 8);
#pragma unroll
    for (int u = 0; u < 4; ++u)
#pragma unroll
      for (int j = 0; j < 8; ++j) acc[j] += bf2f((u16)v[u][j]);
  }
  for (; e < cnt; ++e) {
    bf16x8 v0 = *(const bf16x8*)(xbf + (size_t)lst[e] * NF + hl * 8);
#pragma unroll
    for (int j = 0; j < 8; ++j) acc[j] += bf2f((u16)v0[j]);
  }
  bf16x8 o;
#pragma unroll
  for (int j = 0; j < 8; ++j) o[j] = (short)f2bf(acc[j]);
  *outp = o;
}

// ---------------- GEMM: 2-deep pipeline with COUNTED vmcnt + raw s_barrier ----------------
// T4 mechanism: next tile's 8 global_load_lds stay in flight ACROSS the barrier
// (s_waitcnt vmcnt(8) waits only for the current tile's loads; __syncthreads would
// drain vmcnt(0) and kill the prefetch — the R11/R12 failure mode). sched_barrier(0)
// fences ds_read hoisting around the raw barriers (ERRATA #18).
template <int K, bool RELU, bool OUTF32, bool STATS>
__global__ __launch_bounds__(256) void gemm_bt(const u16* __restrict__ Ab,
                                               const u16* __restrict__ Bt,
                                               const float* __restrict__ bias,
                                               void* __restrict__ Cp, int Mstore,
                                               float* __restrict__ parts) {
  __shared__ __align__(16) u16 As[2][128 * 64];
  __shared__ __align__(16) u16 Bs[2][128 * 64];
  __shared__ float sred[256];
  const int tid = threadIdx.x;
  const int lane = tid & 63;
  const int wid = tid >> 6;
  const int wr = wid >> 1, wc = wid & 1;

  const int nwg = gridDim.x;
  const int q = nwg >> 3, r = nwg & 7;
  const int xcd = blockIdx.x & 7, idx = blockIdx.x >> 3;
  const int work = (xcd < r ? xcd * (q + 1) : r * (q + 1) + (xcd - r) * q) + idx;
  const int brow = (work >> 2) * 128;
  const int bcol = (work & 3) * 128;

  f32x4 acc[4][4] = {};   // acc[n][m] — transposed tile

  const int lrow = lane >> 3;
  const int lkc = ((lane & 7) ^ (lrow & 7)) * 8;
  const int nt = K / 64;

  if (STATS) {
    if (tid < 64) ((float4*)sred)[tid] = (float4){0.f, 0.f, 0.f, 0.f};
  }

  // prologue: stage tile 0 into buffer 0 (8 gload_lds per wave)
#pragma unroll
  for (int i = 0; i < 4; ++i) {
    int c = i * 4 + wid;
    int row = c * 8 + lrow;
    async16(Ab + (size_t)(brow + row) * K + lkc, &As[0][c * 512]);
    async16(Bt + (size_t)(bcol + row) * K + lkc, &Bs[0][c * 512]);
  }

  int cur = 0;
  for (int t = 0; t < nt; ++t) {
    // issue next tile's loads (8 per wave) into the other buffer
    if (t + 1 < nt) {
      const int k0 = (t + 1) * 64;
#pragma unroll
      for (int i = 0; i < 4; ++i) {
        int c = i * 4 + wid;
        int row = c * 8 + lrow;
        async16(Ab + (size_t)(brow + row) * K + k0 + lkc, &As[cur ^ 1][c * 512]);
        async16(Bt + (size_t)(bcol + row) * K + k0 + lkc, &Bs[cur ^ 1][c * 512]);
      }
      asm volatile("s_waitcnt vmcnt(8)" ::: "memory");   // tile t done; 8 newest in flight
    } else {
      asm volatile("s_waitcnt vmcnt(0)" ::: "memory");   // last tile: drain
    }
    __builtin_amdgcn_sched_barrier(0);
    __builtin_amdgcn_s_barrier();                        // raw: no implicit vmcnt drain
    __builtin_amdgcn_sched_barrier(0);

    // compute tile t from buf[cur]
#pragma unroll
    for (int ks = 0; ks < 2; ++ks) {
      bf16x8 af[4], bfr[4];
      const int rchunk = ((ks << 2) + (lane >> 4)) ^ (lane & 7);
#pragma unroll
      for (int m = 0; m < 4; ++m)
        af[m] = *(const bf16x8*)&As[cur][(wr * 64 + m * 16 + (lane & 15)) * 64 + rchunk * 8];
#pragma unroll
      for (int n = 0; n < 4; ++n)
        bfr[n] = *(const bf16x8*)&Bs[cur][(wc * 64 + n * 16 + (lane & 15)) * 64 + rchunk * 8];
#pragma unroll
      for (int n = 0; n < 4; ++n)
#pragma unroll
        for (int m = 0; m < 4; ++m)
          acc[n][m] = __builtin_amdgcn_mfma_f32_16x16x32_bf16(bfr[n], af[m], acc[n][m], 0, 0, 0);
    }
    asm volatile("s_waitcnt lgkmcnt(0)" ::: "memory");   // all ds_reads of buf[cur] done
    __builtin_amdgcn_sched_barrier(0);
    __builtin_amdgcn_s_barrier();                        // now buf[cur] may be overwritten
    __builtin_amdgcn_sched_barrier(0);
    cur ^= 1;
  }

  // epilogue: lane holds 4 consecutive C-cols at one row per (n,m)
  const int row_base = brow + wr * 64 + (lane & 15);
  const int col_base = bcol + wc * 64 + ((lane >> 4) << 2);
#pragma unroll
  for (int n = 0; n < 4; ++n) {
    int col = col_base + n * 16;
    float4 bv4 = *(const float4*)&bias[col];
    float s0 = 0.f, s1 = 0.f, s2 = 0.f, s3 = 0.f;
    float q0 = 0.f, q1 = 0.f, q2 = 0.f, q3 = 0.f;
#pragma unroll
    for (int m = 0; m < 4; ++m) {
      int row = row_base + m * 16;
      f32x4 a = acc[n][m];
      float v0 = a[0] + bv4.x, v1 = a[1] + bv4.y, v2 = a[2] + bv4.z, v3 = a[3] + bv4.w;
      if (RELU) {
        v0 = fmaxf(v0, 0.f); v1 = fmaxf(v1, 0.f);
        v2 = fmaxf(v2, 0.f); v3 = fmaxf(v3, 0.f);
      }
      if (row < Mstore) {
        if (OUTF32) {
          float4 o = {v0, v1, v2, v3};
          *(float4*)&((float*)Cp)[(size_t)row * NH + col] = o;
        } else {
          ushort4 o = {f2bf(v0), f2bf(v1), f2bf(v2), f2bf(v3)};
          *(ushort4*)&((u16*)Cp)[(size_t)row * NH + col] = o;
        }
      }
      if (STATS && row < NNODES) {
        s0 += v0; s1 += v1; s2 += v2; s3 += v3;
        q0 += v0 * v0; q1 += v1 * v1; q2 += v2 * v2; q3 += v3 * v3;
      }
    }
    if (STATS) {
#pragma unroll
      for (int msk = 1; msk < 16; msk <<= 1) {
        s0 += __shfl_xor(s0, msk); s1 += __shfl_xor(s1, msk);
        s2 += __shfl_xor(s2, msk); s3 += __shfl_xor(s3, msk);
        q0 += __shfl_xor(q0, msk); q1 += __shfl_xor(q1, msk);
        q2 += __shfl_xor(q2, msk); q3 += __shfl_xor(q3, msk);
      }
      if ((lane & 15) == 0) {
        int lc = wc * 64 + n * 16 + ((lane >> 4) << 2);
        atomicAdd(&sred[lc + 0], s0); atomicAdd(&sred[lc + 1], s1);
        atomicAdd(&sred[lc + 2], s2); atomicAdd(&sred[lc + 3], s3);
        atomicAdd(&sred[128 + lc + 0], q0); atomicAdd(&sred[128 + lc + 1], q1);
        atomicAdd(&sred[128 + lc + 2], q2); atomicAdd(&sred[128 + lc + 3], q3);
      }
    }
  }
  if (STATS) {
    __syncthreads();
    if (tid < 128) {
      parts[(size_t)work * 256 + tid] = sred[tid];
      parts[(size_t)work * 256 + 128 + tid] = sred[128 + tid];
    }
  }
}

// ---------------- stats+bn merged ----------------
__global__ __launch_bounds__(256) void stats_bn(const float* __restrict__ parts,
                                                const float* __restrict__ gamma,
                                                const float* __restrict__ beta,
                                                float* __restrict__ a_arr,
                                                float* __restrict__ c_arr,
                                                int* __restrict__ err) {
  int c = blockIdx.x * 256 + threadIdx.x;   // 0..511
  int grp = (c >> 7) & 3, cl = c & 127;
  float s = 0.f, qq = 0.f;
  for (int rb = 0; rb < NRB; ++rb) {
    const float* p = parts + (size_t)((rb << 2) + grp) * 256 + cl;
    s += p[0];
    qq += p[128];
  }
  float mean = s * (1.f / NNODES);
  float var = qq * (1.f / NNODES) - mean * mean;
  if (!(mean == mean) || !(var == var) ||
      fabsf(mean) > 1e20f || var > 1e20f || var < -1e-2f)
    err[0] = 2;
  if (var < 0.f) var = 0.f;
  float a = gamma[c] * rsqrtf(var + BN_EPS);
  a_arr[c] = a;
  c_arr[c] = beta[c] - mean * a;
}

// ---------------- fold BN into W2 ----------------
__global__ __launch_bounds__(256) void fold_w2(const float* __restrict__ W2,
                                               const float* __restrict__ b2,
                                               const float* __restrict__ a_arr,
                                               const float* __restrict__ c_arr,
                                               u16* __restrict__ W2pt,
                                               float* __restrict__ bias2p) {
  int n = blockIdx.x;
  int t = threadIdx.x;
  float accv = 0.f;
  for (int k = t; k < NH; k += 256) {
    float w = W2[(size_t)k * NH + n];
    W2pt[(size_t)n * NH + k] = f2bf(a_arr[k] * w);
    accv += c_arr[k] * w;
  }
  __shared__ float red[256];
  red[t] = accv;
  __syncthreads();
  for (int s = 128; s > 0; s >>= 1) {
    if (t < s) red[t] += red[t + s];
    __syncthreads();
  }
  if (t == 0) bias2p[n] = b2[n] + red[0];
}

// ---------------- diagnostics ----------------
__global__ __launch_bounds__(256) void write_sentinel(float* __restrict__ out, int n, float val) {
  int stride = gridDim.x * blockDim.x;
  for (int i = blockIdx.x * blockDim.x + threadIdx.x; i < n; i += stride) out[i] = val;
}

__global__ __launch_bounds__(256) void apply_err(const int* __restrict__ err,
                                                 float* __restrict__ out, int n) {
  if (err[0] == 0) return;
  int stride = gridDim.x * blockDim.x;
  for (int i = blockIdx.x * blockDim.x + threadIdx.x; i < n; i += stride) out[i] = -500000.f;
}

extern "C" void kernel_launch(void* const* d_in, const int* in_sizes, int n_in,
                              void* d_out, int out_size, void* d_ws, size_t ws_size,
                              hipStream_t stream) {
  const float* x     = (const float*)d_in[0];
  const int*   ei    = (const int*)d_in[1];
  const float* W1    = (const float*)d_in[2];
  const float* b1    = (const float*)d_in[3];
  const float* gamma = (const float*)d_in[4];
  const float* beta  = (const float*)d_in[5];
  const float* W2    = (const float*)d_in[6];
  const float* b2    = (const float*)d_in[7];
  float* out = (float*)d_out;
  const int E = in_sizes[1] / 2;   // 800000

  char* ws = (char*)d_ws;
  size_t off = 0;
  auto alloc = [&](size_t bytes) {
    char* p = ws + off;
    off += (bytes + 255) & ~(size_t)255;
    return p;
  };
  u16*   xbf    = (u16*)alloc((size_t)NNODES * NF * 2);     // 25.6 MB
  u16*   hpad   = (u16*)alloc((size_t)MPAD * NF * 2);       // 25.6 MB
  u16*   h1     = (u16*)alloc((size_t)MPAD * NH * 2);       // 51.25 MB
  u16*   W1t    = (u16*)alloc((size_t)NH * NF * 2);
  u16*   W2pt   = (u16*)alloc((size_t)NH * NH * 2);
  int*   srcs   = (int*)alloc((size_t)NNODES * CAP * 4);    // 19.2 MB buckets
  int*   cw     = (int*)alloc((size_t)NNODES * 4);          // cursor == final count
  float* parts  = (float*)alloc((size_t)NRB * 4 * 256 * 4);
  int*   err    = (int*)alloc(8);
  float* a_arr  = (float*)alloc(NH * 4);
  float* c_arr  = (float*)alloc(NH * 4);
  float* bias2p = (float*)alloc(NH * 4);

  if (off > ws_size) {
    write_sentinel<<<2048, 256, 0, stream>>>(out, out_size,
        1.0e7f + 1048576.0f * (float)(ws_size >> 20));
    return;
  }

  hipMemsetAsync(cw, 0, (size_t)NNODES * 4, stream);
  hipMemsetAsync(err, 0, 8, stream);

  bucket_fill<<<1024, 256, 0, stream>>>(ei, E, cw, srcs, err);
  conv_tr_kernel<<<2560, 256, 0, stream>>>(x, xbf, W1, W1t);
  gather_kernel<<<MPAD / 8, 256, 0, stream>>>(xbf, srcs, cw, hpad);

  const int nwg = NRB * 4;   // 1564
  gemm_bt<NF, true, false, true><<<nwg, 256, 0, stream>>>(hpad, W1t, b1, h1, MPAD, parts);

  stats_bn<<<2, 256, 0, stream>>>(parts, gamma, beta, a_arr, c_arr, err);
  fold_w2<<<NH, 256, 0, stream>>>(W2, b2, a_arr, c_arr, W2pt, bias2p);

  gemm_bt<NH, false, true, false><<<nwg, 256, 0, stream>>>(h1, W2pt, bias2p, out, NNODES, nullptr);

  apply_err<<<2048, 256, 0, stream>>>(err, out, out_size);
}

// Round 23
// 232.225 us; speedup vs baseline: 1.0230x; 1.0230x over previous
//
#include <hip/hip_runtime.h>

#define NNODES 50000
#define NF 256
#define NH 512
#define MPAD 50048   // 391 * 128
#define NRB 391      // MPAD/128 row-blocks
#define BN_EPS 1e-5f
#define CAP 96       // bucket capacity; P(deg>96 | E=800K uniform) < 1e-40, overflow -> err sentinel

typedef unsigned short u16;
typedef __attribute__((ext_vector_type(8))) short bf16x8;
typedef __attribute__((ext_vector_type(4))) float f32x4;

__device__ __forceinline__ float bf2f(u16 u) {
  union { unsigned int i; float f; } v; v.i = ((unsigned int)u) << 16; return v.f;
}
__device__ __forceinline__ u16 f2bf(float f) {
  union { float ff; unsigned int i; } v; v.ff = f;
  unsigned int r = v.i + 0x7FFFu + ((v.i >> 16) & 1u);
  return (u16)(r >> 16);
}

__device__ __forceinline__ void async16(const void* g, void* l) {
  __builtin_amdgcn_global_load_lds(
      (const __attribute__((address_space(1))) unsigned int*)g,
      (__attribute__((address_space(3))) unsigned int*)l, 16, 0, 0);
}

// ---------------- conv_x + transpose_w1: pure streaming ----------------
__global__ __launch_bounds__(256) void conv_tr_kernel(const float* __restrict__ x,
                                                      u16* __restrict__ xbf,
                                                      const float* __restrict__ W1,
                                                      u16* __restrict__ W1t) {
  const int b = blockIdx.x;
  if (b < 2048) {
    const size_t n8 = (size_t)NNODES * NF / 8;
    size_t stride = (size_t)2048 * 256;
    for (size_t i = b * (size_t)256 + threadIdx.x; i < n8; i += stride) {
      float4 a = ((const float4*)x)[2 * i];
      float4 c = ((const float4*)x)[2 * i + 1];
      ushort4 lo, hi;
      lo.x = f2bf(a.x); lo.y = f2bf(a.y); lo.z = f2bf(a.z); lo.w = f2bf(a.w);
      hi.x = f2bf(c.x); hi.y = f2bf(c.y); hi.z = f2bf(c.z); hi.w = f2bf(c.w);
      ((ushort4*)xbf)[2 * i] = lo;
      ((ushort4*)xbf)[2 * i + 1] = hi;
    }
  } else {
    int idx = (b - 2048) * 256 + threadIdx.x;
    int n = idx >> 8;
    int k = idx & 255;
    W1t[(size_t)n * NF + k] = f2bf(W1[(size_t)k * NH + n]);
  }
}

// ---------------- bucket fill: ONE atomic pass; u16 buckets (src<65536) halve the
// scattered-write footprint (9.6 MB region -> better L2 residency, fewer dirty lines)
__global__ __launch_bounds__(256) void bucket_fill(const int* __restrict__ ei, int E,
                                                   int* __restrict__ cw,
                                                   u16* __restrict__ srcs,
                                                   int* __restrict__ err) {
  __shared__ int sf;
  if (threadIdx.x < 64) {
    unsigned long long bb = __ballot(ei[2 * threadIdx.x + 1] == 0);
    if (threadIdx.x == 0) sf = (bb == ~0ull) ? 1 : 0;
  }
  __syncthreads();
  const int is64 = sf;
  const int gtid = blockIdx.x * 256 + threadIdx.x;
  const int stride = gridDim.x * 256;
  if (is64) {
    const int4* s4 = (const int4*)ei;                 // edges 2p,2p+1 in .x,.z
    const int4* d4 = (const int4*)(ei + 2 * (size_t)E);
    int np = E >> 1;
    for (int p = gtid; p < np; p += stride) {
      int4 sv = s4[p], dv = d4[p];
      if ((unsigned)sv.x < NNODES && (unsigned)dv.x < NNODES) {
        int pos = atomicAdd(&cw[dv.x], 1);
        if (pos < CAP) srcs[(size_t)dv.x * CAP + pos] = (u16)sv.x; else err[0] = 4;
      }
      if ((unsigned)sv.z < NNODES && (unsigned)dv.z < NNODES) {
        int pos = atomicAdd(&cw[dv.z], 1);
        if (pos < CAP) srcs[(size_t)dv.z * CAP + pos] = (u16)sv.z; else err[0] = 4;
      }
    }
    for (int e = (np << 1) + gtid; e < E; e += stride) {
      int src = ei[2 * e], dst = ei[2 * (size_t)E + 2 * e];
      if ((unsigned)src >= NNODES || (unsigned)dst >= NNODES) continue;
      int pos = atomicAdd(&cw[dst], 1);
      if (pos < CAP) srcs[(size_t)dst * CAP + pos] = (u16)src; else err[0] = 4;
    }
  } else {
    const int4* s4 = (const int4*)ei;
    const int4* d4 = (const int4*)(ei + E);
    int np = E >> 2;
    for (int p = gtid; p < np; p += stride) {
      int4 sv = s4[p], dv = d4[p];
      int ss[4] = {sv.x, sv.y, sv.z, sv.w};
      int dd[4] = {dv.x, dv.y, dv.z, dv.w};
#pragma unroll
      for (int j = 0; j < 4; ++j) {
        if ((unsigned)ss[j] < NNODES && (unsigned)dd[j] < NNODES) {
          int pos = atomicAdd(&cw[dd[j]], 1);
          if (pos < CAP) srcs[(size_t)dd[j] * CAP + pos] = (u16)ss[j]; else err[0] = 4;
        }
      }
    }
    for (int e = (np << 2) + gtid; e < E; e += stride) {
      int src = ei[e], dst = ei[(size_t)E + e];
      if ((unsigned)src >= NNODES || (unsigned)dst >= NNODES) continue;
      int pos = atomicAdd(&cw[dst], 1);
      if (pos < CAP) srcs[(size_t)dst * CAP + pos] = (u16)src; else err[0] = 4;
    }
  }
}

// ---------------- gather-reduce from u16 buckets: 2 nodes/wave, 32 lanes/node ----------------
__global__ __launch_bounds__(256) void gather_kernel(const u16* __restrict__ xbf,
                                                     const u16* __restrict__ srcs,
                                                     const int* __restrict__ cw,
                                                     u16* __restrict__ hpad) {
  const int hl = threadIdx.x & 31;
  const int node = blockIdx.x * 8 + (threadIdx.x >> 5);
  if (node >= MPAD) return;
  bf16x8* outp = (bf16x8*)(hpad + (size_t)node * NF + hl * 8);
  if (node >= NNODES) {
    bf16x8 z = {0, 0, 0, 0, 0, 0, 0, 0};
    *outp = z;
    return;
  }
  bf16x8 sv = *(const bf16x8*)(xbf + (size_t)node * NF + hl * 8);
  float acc[8];
#pragma unroll
  for (int j = 0; j < 8; ++j) acc[j] = bf2f((u16)sv[j]);
  int cnt = cw[node];
  if (cnt > CAP) cnt = CAP;
  const u16* lst = srcs + (size_t)node * CAP;
  int e = 0;
  for (; e + 3 < cnt; e += 4) {
    bf16x8 v[4];
#pragma unroll
    for (int u = 0; u < 4; ++u)
      v[u] = *(const bf16x8*)(xbf + (size_t)lst[e + u] * NF + hl * 8);
#pragma unroll
    for (int u = 0; u < 4; ++u)
#pragma unroll
      for (int j = 0; j < 8; ++j) acc[j] += bf2f((u16)v[u][j]);
  }
  for (; e < cnt; ++e) {
    bf16x8 v0 = *(const bf16x8*)(xbf + (size_t)lst[e] * NF + hl * 8);
#pragma unroll
    for (int j = 0; j < 8; ++j) acc[j] += bf2f((u16)v0[j]);
  }
  bf16x8 o;
#pragma unroll
  for (int j = 0; j < 8; ++j) o[j] = (short)f2bf(acc[j]);
  *outp = o;
}

// ---------------- GEMM (R18/R21-proven): single-buffered LDS (4 blocks/CU),
// swapped-operand MFMA, pre-swizzled gload_lds + swizzled ds_read, m204 XCD
// chunking, vectorized stores, fused BN stats partials ----------------
template <int K, bool RELU, bool OUTF32, bool STATS>
__global__ __launch_bounds__(256) void gemm_bt(const u16* __restrict__ Ab,
                                               const u16* __restrict__ Bt,
                                               const float* __restrict__ bias,
                                               void* __restrict__ Cp, int Mstore,
                                               float* __restrict__ parts) {
  __shared__ __align__(16) u16 As[128 * 64];
  __shared__ __align__(16) u16 Bs[128 * 64];
  __shared__ float sred[256];
  const int tid = threadIdx.x;
  const int lane = tid & 63;
  const int wid = tid >> 6;
  const int wr = wid >> 1, wc = wid & 1;

  const int nwg = gridDim.x;
  const int q = nwg >> 3, r = nwg & 7;
  const int xcd = blockIdx.x & 7, idx = blockIdx.x >> 3;
  const int work = (xcd < r ? xcd * (q + 1) : r * (q + 1) + (xcd - r) * q) + idx;
  const int brow = (work >> 2) * 128;
  const int bcol = (work & 3) * 128;

  f32x4 acc[4][4] = {};   // acc[n][m] — transposed tile

  const int lrow = lane >> 3;
  const int lkc = ((lane & 7) ^ (lrow & 7)) * 8;
  const int nt = K / 64;

  if (STATS) {
    if (tid < 64) ((float4*)sred)[tid] = (float4){0.f, 0.f, 0.f, 0.f};
  }

  for (int t = 0; t < nt; ++t) {
    const int k0 = t * 64;
#pragma unroll
    for (int i = 0; i < 4; ++i) {
      int c = i * 4 + wid;
      int row = c * 8 + lrow;
      async16(Ab + (size_t)(brow + row) * K + k0 + lkc, &As[c * 512]);
      async16(Bt + (size_t)(bcol + row) * K + k0 + lkc, &Bs[c * 512]);
    }
    __syncthreads();   // drain staging
#pragma unroll
    for (int ks = 0; ks < 2; ++ks) {
      bf16x8 af[4], bfr[4];
      const int rchunk = ((ks << 2) + (lane >> 4)) ^ (lane & 7);
#pragma unroll
      for (int m = 0; m < 4; ++m)
        af[m] = *(const bf16x8*)&As[(wr * 64 + m * 16 + (lane & 15)) * 64 + rchunk * 8];
#pragma unroll
      for (int n = 0; n < 4; ++n)
        bfr[n] = *(const bf16x8*)&Bs[(wc * 64 + n * 16 + (lane & 15)) * 64 + rchunk * 8];
#pragma unroll
      for (int n = 0; n < 4; ++n)
#pragma unroll
        for (int m = 0; m < 4; ++m)
          acc[n][m] = __builtin_amdgcn_mfma_f32_16x16x32_bf16(bfr[n], af[m], acc[n][m], 0, 0, 0);
    }
    __syncthreads();   // protect LDS before next-tile overwrite
  }

  // epilogue: lane holds 4 consecutive C-cols at one row per (n,m)
  const int row_base = brow + wr * 64 + (lane & 15);
  const int col_base = bcol + wc * 64 + ((lane >> 4) << 2);
#pragma unroll
  for (int n = 0; n < 4; ++n) {
    int col = col_base + n * 16;
    float4 bv4 = *(const float4*)&bias[col];
    float s0 = 0.f, s1 = 0.f, s2 = 0.f, s3 = 0.f;
    float q0 = 0.f, q1 = 0.f, q2 = 0.f, q3 = 0.f;
#pragma unroll
    for (int m = 0; m < 4; ++m) {
      int row = row_base + m * 16;
      f32x4 a = acc[n][m];
      float v0 = a[0] + bv4.x, v1 = a[1] + bv4.y, v2 = a[2] + bv4.z, v3 = a[3] + bv4.w;
      if (RELU) {
        v0 = fmaxf(v0, 0.f); v1 = fmaxf(v1, 0.f);
        v2 = fmaxf(v2, 0.f); v3 = fmaxf(v3, 0.f);
      }
      if (row < Mstore) {
        if (OUTF32) {
          float4 o = {v0, v1, v2, v3};
          *(float4*)&((float*)Cp)[(size_t)row * NH + col] = o;
        } else {
          ushort4 o = {f2bf(v0), f2bf(v1), f2bf(v2), f2bf(v3)};
          *(ushort4*)&((u16*)Cp)[(size_t)row * NH + col] = o;
        }
      }
      if (STATS && row < NNODES) {
        s0 += v0; s1 += v1; s2 += v2; s3 += v3;
        q0 += v0 * v0; q1 += v1 * v1; q2 += v2 * v2; q3 += v3 * v3;
      }
    }
    if (STATS) {
#pragma unroll
      for (int msk = 1; msk < 16; msk <<= 1) {
        s0 += __shfl_xor(s0, msk); s1 += __shfl_xor(s1, msk);
        s2 += __shfl_xor(s2, msk); s3 += __shfl_xor(s3, msk);
        q0 += __shfl_xor(q0, msk); q1 += __shfl_xor(q1, msk);
        q2 += __shfl_xor(q2, msk); q3 += __shfl_xor(q3, msk);
      }
      if ((lane & 15) == 0) {
        int lc = wc * 64 + n * 16 + ((lane >> 4) << 2);
        atomicAdd(&sred[lc + 0], s0); atomicAdd(&sred[lc + 1], s1);
        atomicAdd(&sred[lc + 2], s2); atomicAdd(&sred[lc + 3], s3);
        atomicAdd(&sred[128 + lc + 0], q0); atomicAdd(&sred[128 + lc + 1], q1);
        atomicAdd(&sred[128 + lc + 2], q2); atomicAdd(&sred[128 + lc + 3], q3);
      }
    }
  }
  if (STATS) {
    __syncthreads();
    if (tid < 128) {
      parts[(size_t)work * 256 + tid] = sred[tid];
      parts[(size_t)work * 256 + 128 + tid] = sred[128 + tid];
    }
  }
}

// ---------------- stats+bn merged ----------------
__global__ __launch_bounds__(256) void stats_bn(const float* __restrict__ parts,
                                                const float* __restrict__ gamma,
                                                const float* __restrict__ beta,
                                                float* __restrict__ a_arr,
                                                float* __restrict__ c_arr,
                                                int* __restrict__ err) {
  int c = blockIdx.x * 256 + threadIdx.x;   // 0..511
  int grp = (c >> 7) & 3, cl = c & 127;
  float s = 0.f, qq = 0.f;
  for (int rb = 0; rb < NRB; ++rb) {
    const float* p = parts + (size_t)((rb << 2) + grp) * 256 + cl;
    s += p[0];
    qq += p[128];
  }
  float mean = s * (1.f / NNODES);
  float var = qq * (1.f / NNODES) - mean * mean;
  if (!(mean == mean) || !(var == var) ||
      fabsf(mean) > 1e20f || var > 1e20f || var < -1e-2f)
    err[0] = 2;
  if (var < 0.f) var = 0.f;
  float a = gamma[c] * rsqrtf(var + BN_EPS);
  a_arr[c] = a;
  c_arr[c] = beta[c] - mean * a;
}

// ---------------- fold BN into W2 ----------------
__global__ __launch_bounds__(256) void fold_w2(const float* __restrict__ W2,
                                               const float* __restrict__ b2,
                                               const float* __restrict__ a_arr,
                                               const float* __restrict__ c_arr,
                                               u16* __restrict__ W2pt,
                                               float* __restrict__ bias2p) {
  int n = blockIdx.x;
  int t = threadIdx.x;
  float accv = 0.f;
  for (int k = t; k < NH; k += 256) {
    float w = W2[(size_t)k * NH + n];
    W2pt[(size_t)n * NH + k] = f2bf(a_arr[k] * w);
    accv += c_arr[k] * w;
  }
  __shared__ float red[256];
  red[t] = accv;
  __syncthreads();
  for (int s = 128; s > 0; s >>= 1) {
    if (t < s) red[t] += red[t + s];
    __syncthreads();
  }
  if (t == 0) bias2p[n] = b2[n] + red[0];
}

// ---------------- diagnostics ----------------
__global__ __launch_bounds__(256) void write_sentinel(float* __restrict__ out, int n, float val) {
  int stride = gridDim.x * blockDim.x;
  for (int i = blockIdx.x * blockDim.x + threadIdx.x; i < n; i += stride) out[i] = val;
}

__global__ __launch_bounds__(256) void apply_err(const int* __restrict__ err,
                                                 float* __restrict__ out, int n) {
  if (err[0] == 0) return;
  int stride = gridDim.x * blockDim.x;
  for (int i = blockIdx.x * blockDim.x + threadIdx.x; i < n; i += stride) out[i] = -500000.f;
}

extern "C" void kernel_launch(void* const* d_in, const int* in_sizes, int n_in,
                              void* d_out, int out_size, void* d_ws, size_t ws_size,
                              hipStream_t stream) {
  const float* x     = (const float*)d_in[0];
  const int*   ei    = (const int*)d_in[1];
  const float* W1    = (const float*)d_in[2];
  const float* b1    = (const float*)d_in[3];
  const float* gamma = (const float*)d_in[4];
  const float* beta  = (const float*)d_in[5];
  const float* W2    = (const float*)d_in[6];
  const float* b2    = (const float*)d_in[7];
  float* out = (float*)d_out;
  const int E = in_sizes[1] / 2;   // 800000

  char* ws = (char*)d_ws;
  size_t off = 0;
  auto alloc = [&](size_t bytes) {
    char* p = ws + off;
    off += (bytes + 255) & ~(size_t)255;
    return p;
  };
  u16*   xbf    = (u16*)alloc((size_t)NNODES * NF * 2);     // 25.6 MB
  u16*   hpad   = (u16*)alloc((size_t)MPAD * NF * 2);       // 25.6 MB
  u16*   h1     = (u16*)alloc((size_t)MPAD * NH * 2);       // 51.25 MB
  u16*   W1t    = (u16*)alloc((size_t)NH * NF * 2);
  u16*   W2pt   = (u16*)alloc((size_t)NH * NH * 2);
  u16*   srcs   = (u16*)alloc((size_t)NNODES * CAP * 2);    // 9.6 MB u16 buckets
  int*   cw     = (int*)alloc((size_t)NNODES * 4);          // cursor == final count
  float* parts  = (float*)alloc((size_t)NRB * 4 * 256 * 4);
  int*   err    = (int*)alloc(8);
  float* a_arr  = (float*)alloc(NH * 4);
  float* c_arr  = (float*)alloc(NH * 4);
  float* bias2p = (float*)alloc(NH * 4);

  if (off > ws_size) {
    write_sentinel<<<2048, 256, 0, stream>>>(out, out_size,
        1.0e7f + 1048576.0f * (float)(ws_size >> 20));
    return;
  }

  hipMemsetAsync(cw, 0, (size_t)NNODES * 4, stream);
  hipMemsetAsync(err, 0, 8, stream);

  bucket_fill<<<1024, 256, 0, stream>>>(ei, E, cw, srcs, err);
  conv_tr_kernel<<<2560, 256, 0, stream>>>(x, xbf, W1, W1t);
  gather_kernel<<<MPAD / 8, 256, 0, stream>>>(xbf, srcs, cw, hpad);

  const int nwg = NRB * 4;   // 1564
  gemm_bt<NF, true, false, true><<<nwg, 256, 0, stream>>>(hpad, W1t, b1, h1, MPAD, parts);

  stats_bn<<<2, 256, 0, stream>>>(parts, gamma, beta, a_arr, c_arr, err);
  fold_w2<<<NH, 256, 0, stream>>>(W2, b2, a_arr, c_arr, W2pt, bias2p);

  gemm_bt<NH, false, true, false><<<nwg, 256, 0, stream>>>(h1, W2pt, bias2p, out, NNODES, nullptr);

  apply_err<<<2048, 256, 0, stream>>>(err, out, out_size);
}